// Round 1
// baseline (212.401 us; speedup 1.0000x reference)
//
#include <hip/hip_runtime.h>

// ScorePredictor: per-edge dot product  score[e] = dot(h[src[e]], h[dst[e]])
// N=100000, E=1600000, D=128 (fp32).
//
// Layout: 32 lanes (half-wave) per edge; each lane loads one float4 from the
// src row and one from the dst row (32*4 = 128 floats = whole row, fully
// coalesced 512B segment). Partial dot reduced with 5 shfl_xor steps (masks
// < 32 keep each half-wave group independent inside the 64-lane wave).

#define FEAT_D 128

__global__ __launch_bounds__(256) void edge_dot_kernel(
    const float* __restrict__ h,
    const int*   __restrict__ src,
    const int*   __restrict__ dst,
    float*       __restrict__ out,
    int E)
{
    int tid  = blockIdx.x * blockDim.x + threadIdx.x;
    int edge = tid >> 5;          // 32 threads per edge
    int lane = tid & 31;
    if (edge >= E) return;

    int s = src[edge];
    int d = dst[edge];

    const float4* __restrict__ hs =
        reinterpret_cast<const float4*>(h + (size_t)s * FEAT_D);
    const float4* __restrict__ hd =
        reinterpret_cast<const float4*>(h + (size_t)d * FEAT_D);

    float4 a = hs[lane];
    float4 b = hd[lane];

    float p = a.x * b.x + a.y * b.y + a.z * b.z + a.w * b.w;

    // Reduce across the 32-lane group (xor masks < 32 stay in-group).
    p += __shfl_xor(p, 16, 64);
    p += __shfl_xor(p,  8, 64);
    p += __shfl_xor(p,  4, 64);
    p += __shfl_xor(p,  2, 64);
    p += __shfl_xor(p,  1, 64);

    if (lane == 0) out[edge] = p;
}

extern "C" void kernel_launch(void* const* d_in, const int* in_sizes, int n_in,
                              void* d_out, int out_size, void* d_ws, size_t ws_size,
                              hipStream_t stream) {
    const float* h   = (const float*)d_in[0];
    const int*   src = (const int*)d_in[1];
    const int*   dst = (const int*)d_in[2];
    float*       out = (float*)d_out;

    int E = in_sizes[1];               // 1,600,000

    const int threads = 256;           // 8 edges per block
    long long total   = (long long)E * 32;
    int blocks        = (int)((total + threads - 1) / threads);

    edge_dot_kernel<<<blocks, threads, 0, stream>>>(h, src, dst, out, E);
}